// Round 6
// baseline (463.989 us; speedup 1.0000x reference)
//
#include <hip/hip_runtime.h>
#include <hip/hip_bf16.h>
#include <stdint.h>

typedef __hip_bfloat16 bf16;
typedef __bf16 bf16x8 __attribute__((ext_vector_type(8)));
typedef float f32x4 __attribute__((ext_vector_type(4)));

#define S_LEN 2048
#define EMB   2048
#define NH    16
#define HD    128

// async global->LDS, 16B per lane. LDS dest must be wave-uniform base + lane*16.
__device__ __forceinline__ void glds16(const void* g, void* l) {
  __builtin_amdgcn_global_load_lds(
      (__attribute__((address_space(1))) void*)g,
      (__attribute__((address_space(3))) void*)l,
      16, 0, 0);
}

// ---------------------------------------------------------------------------
// Kernel 0: fused f32 -> bf16 conversion of x, w_qkv, w_out (one launch).
// ---------------------------------------------------------------------------
__global__ __launch_bounds__(256) void cvt3_k(
    const float* __restrict__ xa, bf16* __restrict__ xo,
    const float* __restrict__ wa, bf16* __restrict__ wo1,
    const float* __restrict__ oa, bf16* __restrict__ oo)
{
  const int bid = blockIdx.x;
  const float* src; bf16* dst; int i;
  if (bid < 8192)       { src = xa; dst = xo;  i = bid * 256 + threadIdx.x; }
  else if (bid < 20480) { src = wa; dst = wo1; i = (bid - 8192) * 256 + threadIdx.x; }
  else                  { src = oa; dst = oo;  i = (bid - 20480) * 256 + threadIdx.x; }
  const float4 v = ((const float4*)src)[i];
  bf16 tmp[4];
  tmp[0] = __float2bfloat16(v.x);
  tmp[1] = __float2bfloat16(v.y);
  tmp[2] = __float2bfloat16(v.z);
  tmp[3] = __float2bfloat16(v.w);
  ((uint2*)dst)[i] = *(const uint2*)tmp;
}

// ---------------------------------------------------------------------------
// Kernel 1: qkv = x @ w_qkv^T + b_qkv  (R1/R5-measured version, ~155 us).
// Q,K scattered into [b,h,s,d]; V written TRANSPOSED into v_t [b,h,d,s].
// ---------------------------------------------------------------------------
__global__ __launch_bounds__(256) void gemm_qkv_k(
    const bf16* __restrict__ x, const bf16* __restrict__ w,
    const float* __restrict__ bias,
    bf16* __restrict__ q_ws, bf16* __restrict__ k_ws, bf16* __restrict__ v_t)
{
  __shared__ alignas(16) bf16 sA[128 * 32];
  __shared__ alignas(16) bf16 sW[128 * 32];
  const int n0 = blockIdx.x * 128;
  const int m0 = blockIdx.y * 128;

  const int t    = threadIdx.x;
  const int lane = t & 63, quad = lane >> 4, l15 = lane & 15;
  const int wave = t >> 6;
  const int wm0  = (wave >> 1) * 64, wn0 = (wave & 1) * 64;
  const int col8 = (t & 3) * 8;

  f32x4 acc[4][4];
#pragma unroll
  for (int mi = 0; mi < 4; mi++)
#pragma unroll
    for (int ni = 0; ni < 4; ni++)
#pragma unroll
      for (int r = 0; r < 4; r++) acc[mi][ni][r] = 0.f;

  for (int k0 = 0; k0 < EMB; k0 += 32) {
#pragma unroll
    for (int i = 0; i < 2; i++) {
      const int lin = i * 256 + t;       // 0..511
      const int row = lin >> 2;          // 0..127
      glds16(x + (size_t)(m0 + row) * EMB + k0 + col8, sA + (size_t)lin * 8);
      glds16(w + (size_t)(n0 + row) * EMB + k0 + col8, sW + (size_t)lin * 8);
    }
    __syncthreads();
    bf16x8 af[4], wf[4];
#pragma unroll
    for (int mi = 0; mi < 4; mi++)
      af[mi] = *(const bf16x8*)(sA + (wm0 + mi * 16 + l15) * 32 + quad * 8);
#pragma unroll
    for (int ni = 0; ni < 4; ni++)
      wf[ni] = *(const bf16x8*)(sW + (wn0 + ni * 16 + l15) * 32 + quad * 8);
#pragma unroll
    for (int mi = 0; mi < 4; mi++)
#pragma unroll
      for (int ni = 0; ni < 4; ni++)
        acc[mi][ni] = __builtin_amdgcn_mfma_f32_16x16x32_bf16(af[mi], wf[ni], acc[mi][ni], 0, 0, 0);
    __syncthreads();
  }

  const int which = n0 >> 11;                 // 0=q,1=k,2=v (whole block same)
  bf16* dst = (which == 0) ? q_ws : ((which == 1) ? k_ws : v_t);

#pragma unroll
  for (int mi = 0; mi < 4; mi++) {
#pragma unroll
    for (int ni = 0; ni < 4; ni++) {
      const int n_g = n0 + wn0 + ni * 16 + l15;
      const int h   = (n_g >> 7) & 15;
      const int d   = n_g & 127;
      const float bv = bias[n_g];
#pragma unroll
      for (int r = 0; r < 4; r++) {
        const int m_g = m0 + wm0 + mi * 16 + quad * 4 + r;
        const int b   = m_g >> 11;
        const int s   = m_g & 2047;
        const size_t idx = (which == 2)
            ? ((size_t)(b * NH + h) * HD + d) * S_LEN + s      // V: [b,h,d,s]
            : ((size_t)(b * NH + h) * S_LEN + s) * HD + d;     // Q/K: [b,h,s,d]
        dst[idx] = __float2bfloat16(acc[mi][ni][r] + bv);
      }
    }
  }
}

// ---------------------------------------------------------------------------
// Kernel 2: causal flash attention. R5 inner structure (K/V dbuf + counted
// vmcnt, XOR-swizzled LDS, setprio, softmax diet) but ONE Q-tile per block,
// grid 512, 2 blocks/CU co-resident (51200 B LDS x2 = 102400 <= 160K).
// qt mapping is complementary under BOTH round-robin (c,c+256) and chunked
// (2k,2k+1) dispatch: s=(c>>8 ^ c)&1, j=(c>>1)&7, qt = s ? j : 15-j.
// Each CU hosts a heavy+light pair -> balanced (34 tile-units) at 2 waves/SIMD.
// ---------------------------------------------------------------------------
__global__ __launch_bounds__(256, 2) void attn_k(
    const bf16* __restrict__ q_ws, const bf16* __restrict__ k_ws,
    const bf16* __restrict__ v_t, bf16* __restrict__ attn_out)
{
  __shared__ alignas(16) bf16 smK[2][8192];
  __shared__ alignas(16) bf16 smV[2][8192];
  __shared__ alignas(16) bf16 smP[4][32 * 72];

  const int t    = threadIdx.x;
  const int lane = t & 63, quad = lane >> 4, l15 = lane & 15;
  const int w    = t >> 6;
  const int c    = blockIdx.x;
  const int sbit = ((c >> 8) ^ c) & 1;
  const int j    = (c >> 1) & 7;
  const int bh   = (c >> 4) & 31;
  const int qt   = sbit ? j : (15 - j);
  const size_t hb = (size_t)bh * (S_LEN * HD);
  bf16* myP = smP[w];
  const float C = 0.12751745f;   // (1/sqrt(128)) * log2(e)
  const int sw = quad ^ ((l15 >> 1) & 3);   // swizzled 16B-slot for K/V reads

  auto stageK = [&](int kv0, bf16* dst) {
#pragma unroll
    for (int i = 0; i < 4; i++) {
      const int lin = i * 256 + t;
      const int cc  = lin >> 8;              // k-chunk 0..3
      const int row = (lin >> 2) & 63;
      const int sl  = (t & 3) ^ ((row >> 1) & 3);   // inverse-swizzled source
      glds16(k_ws + hb + (size_t)(kv0 + row) * HD + cc * 32 + sl * 8,
             dst + (size_t)lin * 8);
    }
  };
  auto stageV = [&](int kv0, bf16* dst) {
#pragma unroll
    for (int i = 0; i < 4; i++) {
      const int lin = i * 256 + t;
      const int cc  = lin >> 9;              // s-chunk 0..1
      const int row = (lin >> 2) & 127;      // d index
      const int sl  = (t & 3) ^ ((row >> 1) & 3);
      glds16(v_t + hb + (size_t)row * S_LEN + kv0 + cc * 32 + sl * 8,
             dst + (size_t)lin * 8);
    }
  };

  const int qbase  = qt * 128;
  const int ntiles = 2 * qt + 2;
  const int wrow0  = qbase + w * 32;
  const int wrow_hi = wrow0 + 31;

  // Q fragments straight from global (registers; no LDS staging)
  bf16x8 qf[2][4];
#pragma unroll
  for (int mi = 0; mi < 2; ++mi)
#pragma unroll
    for (int ks = 0; ks < 4; ++ks)
      qf[mi][ks] = *(const bf16x8*)(q_ws + hb + (size_t)(wrow0 + mi * 16 + l15) * HD + ks * 32 + quad * 8);

  f32x4 o_acc[2][8];
  float m_st[2][4], l_st[2][4];
#pragma unroll
  for (int mi = 0; mi < 2; ++mi) {
#pragma unroll
    for (int dt = 0; dt < 8; ++dt)
#pragma unroll
      for (int r = 0; r < 4; ++r) o_acc[mi][dt][r] = 0.f;
#pragma unroll
    for (int r = 0; r < 4; ++r) { m_st[mi][r] = -1e30f; l_st[mi][r] = 0.f; }
  }

  stageK(0, smK[0]);
  stageV(0, smV[0]);

  for (int tile = 0; tile < ntiles; ++tile) {
    const int cur = tile & 1;
    if (tile + 1 < ntiles) {
      const int kv1 = (tile + 1) * 64;
      stageK(kv1, smK[cur ^ 1]);
      stageV(kv1, smV[cur ^ 1]);
      asm volatile("s_waitcnt vmcnt(8)" ::: "memory");   // keep prefetch in flight
    } else {
      asm volatile("s_waitcnt vmcnt(0)" ::: "memory");
    }
    __builtin_amdgcn_s_barrier();

    const int kv0 = tile * 64;
    if (kv0 <= wrow_hi) {
      // ---- QK^T ----
      f32x4 sc[2][4];
#pragma unroll
      for (int mi = 0; mi < 2; mi++)
#pragma unroll
        for (int ni = 0; ni < 4; ni++)
#pragma unroll
          for (int r = 0; r < 4; r++) sc[mi][ni][r] = 0.f;
      const bf16* kb = smK[cur];
      __builtin_amdgcn_s_setprio(1);
#pragma unroll
      for (int ks = 0; ks < 4; ++ks) {
        bf16x8 kf[4];
#pragma unroll
        for (int ni = 0; ni < 4; ++ni)
          kf[ni] = *(const bf16x8*)(kb + (ks * 64 + ni * 16 + l15) * 32 + sw * 8);
#pragma unroll
        for (int mi = 0; mi < 2; ++mi)
#pragma unroll
          for (int ni = 0; ni < 4; ++ni)
            sc[mi][ni] = __builtin_amdgcn_mfma_f32_16x16x32_bf16(qf[mi][ks], kf[ni], sc[mi][ni], 0, 0, 0);
      }
      __builtin_amdgcn_s_setprio(0);

      // ---- online softmax (exp2 domain, defer-max, per-lane l) ----
#pragma unroll
      for (int mi = 0; mi < 2; ++mi) {
        const int mrow0 = wrow0 + mi * 16;
        const bool needmask = (kv0 + 63 > mrow0);   // wave-uniform
#pragma unroll
        for (int r = 0; r < 4; ++r) {
          const int qg = mrow0 + quad * 4 + r;
          float xs[4];
          float vmax = -1e30f;
          if (needmask) {
#pragma unroll
            for (int ni = 0; ni < 4; ++ni) {
              const int kg = kv0 + ni * 16 + l15;
              float xv = sc[mi][ni][r] * C;
              xv = (kg > qg) ? -1e30f : xv;
              xs[ni] = xv;
              vmax = fmaxf(vmax, xv);
            }
          } else {
#pragma unroll
            for (int ni = 0; ni < 4; ++ni) {
              const float xv = sc[mi][ni][r] * C;
              xs[ni] = xv;
              vmax = fmaxf(vmax, xv);
            }
          }
          float m_old = m_st[mi][r];
          if (!__all(vmax <= m_old + 8.f)) {        // rare after tile 0
#pragma unroll
            for (int off = 1; off < 16; off <<= 1)
              vmax = fmaxf(vmax, __shfl_xor(vmax, off, 64));
            const float mnew  = fmaxf(m_old, vmax);
            const float alpha = __builtin_amdgcn_exp2f(m_old - mnew);
            l_st[mi][r] *= alpha;
#pragma unroll
            for (int dt = 0; dt < 8; ++dt) o_acc[mi][dt][r] *= alpha;
            m_st[mi][r] = mnew;
            m_old = mnew;
          }
          float ps = 0.f;
#pragma unroll
          for (int ni = 0; ni < 4; ++ni) {
            const float p = __builtin_amdgcn_exp2f(xs[ni] - m_old);
            ps += p;
            myP[(mi * 16 + quad * 4 + r) * 72 + ni * 16 + l15] = __float2bfloat16(p);
          }
          l_st[mi][r] += ps;   // per-lane partial; reduced once in epilogue
        }
      }

      // ---- P @ V (per-wave P, no barrier needed) ----
      const bf16* vb = smV[cur];
      __builtin_amdgcn_s_setprio(1);
#pragma unroll
      for (int ks2 = 0; ks2 < 2; ++ks2) {
        bf16x8 pa[2];
#pragma unroll
        for (int mi = 0; mi < 2; ++mi)
          pa[mi] = *(const bf16x8*)(myP + (mi * 16 + l15) * 72 + ks2 * 32 + quad * 8);
#pragma unroll
        for (int dt = 0; dt < 8; ++dt) {
          const bf16x8 vf = *(const bf16x8*)(vb + (ks2 * 128 + dt * 16 + l15) * 32 + sw * 8);
#pragma unroll
          for (int mi = 0; mi < 2; ++mi)
            o_acc[mi][dt] = __builtin_amdgcn_mfma_f32_16x16x32_bf16(pa[mi], vf, o_acc[mi][dt], 0, 0, 0);
        }
      }
      __builtin_amdgcn_s_setprio(0);
    }
    __builtin_amdgcn_s_barrier();   // all reads of buf[cur] done before reuse
  }

  // ---- epilogue: reduce l across the 16-lane row groups, write O/l ----
#pragma unroll
  for (int mi = 0; mi < 2; ++mi) {
#pragma unroll
    for (int r = 0; r < 4; ++r) {
      float l = l_st[mi][r];
#pragma unroll
      for (int off = 1; off < 16; off <<= 1) l += __shfl_xor(l, off, 64);
      const float rl = 1.f / l;
      const int sg = qbase + w * 32 + mi * 16 + quad * 4 + r;
      const size_t rowoff = hb + (size_t)sg * HD;
#pragma unroll
      for (int dt = 0; dt < 8; ++dt)
        attn_out[rowoff + dt * 16 + l15] = __float2bfloat16(o_acc[mi][dt][r] * rl);
    }
  }
}

// ---------------------------------------------------------------------------
// Kernel 3: out = attn @ w_out^T + b_out  (R1/R5-measured version).
// attn stored [b,h,s,d] (logical A[m=b*2048+s][k=h*128+d]). OUTPUT FLOAT32.
// ---------------------------------------------------------------------------
__global__ __launch_bounds__(256) void gemm_out_k(
    const bf16* __restrict__ attn, const bf16* __restrict__ w,
    const float* __restrict__ bias, float* __restrict__ out)
{
  __shared__ alignas(16) bf16 sA[128 * 32];
  __shared__ alignas(16) bf16 sW[128 * 32];
  const int n0 = blockIdx.x * 128;
  const int m0 = blockIdx.y * 128;

  const int t    = threadIdx.x;
  const int lane = t & 63, quad = lane >> 4, l15 = lane & 15;
  const int wave = t >> 6;
  const int wm0  = (wave >> 1) * 64, wn0 = (wave & 1) * 64;
  const int col8 = (t & 3) * 8;

  f32x4 acc[4][4];
#pragma unroll
  for (int mi = 0; mi < 4; mi++)
#pragma unroll
    for (int ni = 0; ni < 4; ni++)
#pragma unroll
      for (int r = 0; r < 4; r++) acc[mi][ni][r] = 0.f;

  for (int k0 = 0; k0 < EMB; k0 += 32) {
    const int kk = k0 + col8;
    const int h  = kk >> 7;          // head (constant across the 8-elt chunk)
    const int dc = kk & 127;
#pragma unroll
    for (int i = 0; i < 2; i++) {
      const int lin = i * 256 + t;       // 0..511
      const int row = lin >> 2;          // 0..127
      const int m   = m0 + row;
      const int b   = m >> 11;
      const int s   = m & 2047;
      glds16(attn + ((size_t)(b * NH + h) * S_LEN + s) * HD + dc, sA + (size_t)lin * 8);
      glds16(w + (size_t)(n0 + row) * EMB + k0 + col8, sW + (size_t)lin * 8);
    }
    __syncthreads();
    bf16x8 af[4], wf[4];
#pragma unroll
    for (int mi = 0; mi < 4; mi++)
      af[mi] = *(const bf16x8*)(sA + (wm0 + mi * 16 + l15) * 32 + quad * 8);
#pragma unroll
    for (int ni = 0; ni < 4; ni++)
      wf[ni] = *(const bf16x8*)(sW + (wn0 + ni * 16 + l15) * 32 + quad * 8);
#pragma unroll
    for (int mi = 0; mi < 4; mi++)
#pragma unroll
      for (int ni = 0; ni < 4; ni++)
        acc[mi][ni] = __builtin_amdgcn_mfma_f32_16x16x32_bf16(af[mi], wf[ni], acc[mi][ni], 0, 0, 0);
    __syncthreads();
  }

#pragma unroll
  for (int mi = 0; mi < 4; mi++) {
#pragma unroll
    for (int ni = 0; ni < 4; ni++) {
      const int n_g = n0 + wn0 + ni * 16 + l15;
      const float bv = bias[n_g];
#pragma unroll
      for (int r = 0; r < 4; r++) {
        const int m_g = m0 + wm0 + mi * 16 + quad * 4 + r;
        out[(size_t)m_g * EMB + n_g] = acc[mi][ni][r] + bv;   // f32 store
      }
    }
  }
}

// ---------------------------------------------------------------------------
// Workspace layout (96 MiB):
//   [ 0,16)  MiB: xb  bf16 (x converted) -> attn output [b,h,s,d] after QKV
//   [16,40)  MiB: wqb bf16 (w_qkv converted)
//   [40,48)  MiB: wob bf16 (w_out converted)
//   [48,64)  MiB: q [b,h,s,d]
//   [64,80)  MiB: k [b,h,s,d]
//   [80,96)  MiB: v_t [b,h,d,s] (written directly transposed by gemm_qkv_k)
// ---------------------------------------------------------------------------
extern "C" void kernel_launch(void* const* d_in, const int* in_sizes, int n_in,
                              void* d_out, int out_size, void* d_ws, size_t ws_size,
                              hipStream_t stream)
{
  const float* x_f     = (const float*)d_in[0];
  // d_in[1] = attn_mask (causal triu) — known analytically, ignored.
  const float* w_qkv_f = (const float*)d_in[2];
  const float* b_qkv   = (const float*)d_in[3];
  const float* w_out_f = (const float*)d_in[4];
  const float* b_out   = (const float*)d_in[5];
  float* out = (float*)d_out;   // reference output dtype is float32

  char* ws = (char*)d_ws;
  const size_t MB = 1024 * 1024;
  bf16* xb   = (bf16*)(ws);
  bf16* wqb  = (bf16*)(ws + 16 * MB);
  bf16* wob  = (bf16*)(ws + 40 * MB);
  bf16* q_ws = (bf16*)(ws + 48 * MB);
  bf16* k_ws = (bf16*)(ws + 64 * MB);
  bf16* v_t  = (bf16*)(ws + 80 * MB);
  bf16* attn = xb;   // xb dead after gemm_qkv_k; distinct from q_ws (no alias)

  cvt3_k<<<dim3(24576), 256, 0, stream>>>(x_f, xb, w_qkv_f, wqb, w_out_f, wob);

  gemm_qkv_k<<<dim3(48, 32), 256, 0, stream>>>(xb, wqb, b_qkv, q_ws, k_ws, v_t);
  attn_k<<<dim3(512), 256, 0, stream>>>(q_ws, k_ws, v_t, attn);
  gemm_out_k<<<dim3(16, 32), 256, 0, stream>>>(attn, wob, b_out, out);
}

// Round 7
// 435.838 us; speedup vs baseline: 1.0646x; 1.0646x over previous
//
#include <hip/hip_runtime.h>
#include <hip/hip_bf16.h>
#include <stdint.h>

typedef __hip_bfloat16 bf16;
typedef __bf16 bf16x8 __attribute__((ext_vector_type(8)));
typedef float f32x4 __attribute__((ext_vector_type(4)));

#define S_LEN 2048
#define EMB   2048
#define NH    16
#define HD    128

// async global->LDS, 16B per lane. LDS dest must be wave-uniform base + lane*16.
__device__ __forceinline__ void glds16(const void* g, void* l) {
  __builtin_amdgcn_global_load_lds(
      (__attribute__((address_space(1))) void*)g,
      (__attribute__((address_space(3))) void*)l,
      16, 0, 0);
}

// ---------------------------------------------------------------------------
// Kernel 0: fused f32 -> bf16 conversion of x, w_qkv, w_out (one launch).
// ---------------------------------------------------------------------------
__global__ __launch_bounds__(256) void cvt3_k(
    const float* __restrict__ xa, bf16* __restrict__ xo,
    const float* __restrict__ wa, bf16* __restrict__ wo1,
    const float* __restrict__ oa, bf16* __restrict__ oo)
{
  const int bid = blockIdx.x;
  const float* src; bf16* dst; int i;
  if (bid < 8192)       { src = xa; dst = xo;  i = bid * 256 + threadIdx.x; }
  else if (bid < 20480) { src = wa; dst = wo1; i = (bid - 8192) * 256 + threadIdx.x; }
  else                  { src = oa; dst = oo;  i = (bid - 20480) * 256 + threadIdx.x; }
  const float4 v = ((const float4*)src)[i];
  bf16 tmp[4];
  tmp[0] = __float2bfloat16(v.x);
  tmp[1] = __float2bfloat16(v.y);
  tmp[2] = __float2bfloat16(v.z);
  tmp[3] = __float2bfloat16(v.w);
  ((uint2*)dst)[i] = *(const uint2*)tmp;
}

// ===========================================================================
// GEMM geometry (both GEMMs): 128x128 tile, BK=64 (was 32), 256 thr/4 waves,
// per-wave 64x64. LDS 32KB: sA[128][64] + sW[128][64], rows 128B.
// BK=64 halves the __syncthreads count (32 iters vs 64) -> half the vmcnt(0)
// barrier drains (the documented ~20% 2-phase stall), 32 MFMA per barrier
// pair. 128B rows would be a 16-way ds_read conflict -> T2 XOR swizzle:
// 16B-chunk index ^= (row&7); inverse-swizzled GLOBAL source + linear glds
// dest + swizzled ds_read (both-sides involution, rule #21) -> 2 lanes/bank.
// ===========================================================================

// ---------------------------------------------------------------------------
// Kernel 1: qkv = x @ w_qkv^T + b_qkv. Q,K scattered into [b,h,s,d];
// V written TRANSPOSED into v_t [b,h,d,s].
// ---------------------------------------------------------------------------
__global__ __launch_bounds__(256) void gemm_qkv_k(
    const bf16* __restrict__ x, const bf16* __restrict__ w,
    const float* __restrict__ bias,
    bf16* __restrict__ q_ws, bf16* __restrict__ k_ws, bf16* __restrict__ v_t)
{
  __shared__ alignas(16) bf16 sA[128 * 64];
  __shared__ alignas(16) bf16 sW[128 * 64];
  const int n0 = blockIdx.x * 128;
  const int m0 = blockIdx.y * 128;

  const int t    = threadIdx.x;
  const int lane = t & 63, quad = lane >> 4, l15 = lane & 15;
  const int wave = t >> 6;
  const int wm0  = (wave >> 1) * 64, wn0 = (wave & 1) * 64;

  f32x4 acc[4][4];
#pragma unroll
  for (int mi = 0; mi < 4; mi++)
#pragma unroll
    for (int ni = 0; ni < 4; ni++)
#pragma unroll
      for (int r = 0; r < 4; r++) acc[mi][ni][r] = 0.f;

  for (int k0 = 0; k0 < EMB; k0 += 64) {
#pragma unroll
    for (int i = 0; i < 4; i++) {
      const int lin = i * 256 + t;              // 0..1023
      const int row = lin >> 3;                 // 0..127
      const int c16 = lin & 7;                  // 16B chunk in row
      const int col = (c16 ^ (row & 7)) * 8;    // inverse-swizzled source col
      glds16(x + (size_t)(m0 + row) * EMB + k0 + col, sA + (size_t)lin * 8);
      glds16(w + (size_t)(n0 + row) * EMB + k0 + col, sW + (size_t)lin * 8);
    }
    __syncthreads();
    bf16x8 af[4][2], wf[4][2];
#pragma unroll
    for (int mi = 0; mi < 4; mi++) {
      const int r = wm0 + mi * 16 + l15;
#pragma unroll
      for (int kk = 0; kk < 2; kk++) {
        const int ch = (kk * 4 + quad) ^ (r & 7);
        af[mi][kk] = *(const bf16x8*)(sA + r * 64 + ch * 8);
      }
    }
#pragma unroll
    for (int ni = 0; ni < 4; ni++) {
      const int r = wn0 + ni * 16 + l15;
#pragma unroll
      for (int kk = 0; kk < 2; kk++) {
        const int ch = (kk * 4 + quad) ^ (r & 7);
        wf[ni][kk] = *(const bf16x8*)(sW + r * 64 + ch * 8);
      }
    }
#pragma unroll
    for (int mi = 0; mi < 4; mi++)
#pragma unroll
      for (int ni = 0; ni < 4; ni++)
#pragma unroll
        for (int kk = 0; kk < 2; kk++)
          acc[mi][ni] = __builtin_amdgcn_mfma_f32_16x16x32_bf16(af[mi][kk], wf[ni][kk], acc[mi][ni], 0, 0, 0);
    __syncthreads();
  }

  const int which = n0 >> 11;                 // 0=q,1=k,2=v (whole block same)
  bf16* dst = (which == 0) ? q_ws : ((which == 1) ? k_ws : v_t);

#pragma unroll
  for (int mi = 0; mi < 4; mi++) {
#pragma unroll
    for (int ni = 0; ni < 4; ni++) {
      const int n_g = n0 + wn0 + ni * 16 + l15;
      const int h   = (n_g >> 7) & 15;
      const int d   = n_g & 127;
      const float bv = bias[n_g];
#pragma unroll
      for (int r = 0; r < 4; r++) {
        const int m_g = m0 + wm0 + mi * 16 + quad * 4 + r;
        const int b   = m_g >> 11;
        const int s   = m_g & 2047;
        const size_t idx = (which == 2)
            ? ((size_t)(b * NH + h) * HD + d) * S_LEN + s      // V: [b,h,d,s]
            : ((size_t)(b * NH + h) * S_LEN + s) * HD + d;     // Q/K: [b,h,s,d]
        dst[idx] = __float2bfloat16(acc[mi][ni][r] + bv);
      }
    }
  }
}

// ---------------------------------------------------------------------------
// Kernel 2: causal flash attention — EXACT R5 version (measured best).
// Balanced heavy+light Q-tile pair per block, grid 256, K/V dbuf + counted
// vmcnt, XOR-swizzled K/V LDS, setprio, exp2 softmax diet.
// ---------------------------------------------------------------------------
__global__ __launch_bounds__(256, 1) void attn_k(
    const bf16* __restrict__ q_ws, const bf16* __restrict__ k_ws,
    const bf16* __restrict__ v_t, bf16* __restrict__ attn_out)
{
  __shared__ alignas(16) bf16 smK[2][8192];
  __shared__ alignas(16) bf16 smV[2][8192];
  __shared__ alignas(16) bf16 smP[4][32 * 72];

  const int t    = threadIdx.x;
  const int lane = t & 63, quad = lane >> 4, l15 = lane & 15;
  const int w    = t >> 6;
  const int bh   = blockIdx.x >> 3;
  const int pr   = blockIdx.x & 7;
  const size_t hb = (size_t)bh * (S_LEN * HD);
  bf16* myP = smP[w];
  const float C = 0.12751745f;   // (1/sqrt(128)) * log2(e)
  const int sw = quad ^ ((l15 >> 1) & 3);   // swizzled 16B-slot for K/V reads

  auto stageK = [&](int kv0, bf16* dst) {
#pragma unroll
    for (int i = 0; i < 4; i++) {
      const int lin = i * 256 + t;
      const int cc  = lin >> 8;              // k-chunk 0..3
      const int row = (lin >> 2) & 63;
      const int sl  = (t & 3) ^ ((row >> 1) & 3);   // inverse-swizzled source
      glds16(k_ws + hb + (size_t)(kv0 + row) * HD + cc * 32 + sl * 8,
             dst + (size_t)lin * 8);
    }
  };
  auto stageV = [&](int kv0, bf16* dst) {
#pragma unroll
    for (int i = 0; i < 4; i++) {
      const int lin = i * 256 + t;
      const int cc  = lin >> 9;              // s-chunk 0..1
      const int row = (lin >> 2) & 127;      // d index
      const int sl  = (t & 3) ^ ((row >> 1) & 3);
      glds16(v_t + hb + (size_t)row * S_LEN + kv0 + cc * 32 + sl * 8,
             dst + (size_t)lin * 8);
    }
  };

  for (int ph = 0; ph < 2; ++ph) {
    const int qt     = ph ? pr : (15 - pr);   // heavy tile first
    const int qbase  = qt * 128;
    const int ntiles = 2 * qt + 2;
    const int wrow0  = qbase + w * 32;
    const int wrow_hi = wrow0 + 31;

    bf16x8 qf[2][4];
#pragma unroll
    for (int mi = 0; mi < 2; ++mi)
#pragma unroll
      for (int ks = 0; ks < 4; ++ks)
        qf[mi][ks] = *(const bf16x8*)(q_ws + hb + (size_t)(wrow0 + mi * 16 + l15) * HD + ks * 32 + quad * 8);

    f32x4 o_acc[2][8];
    float m_st[2][4], l_st[2][4];
#pragma unroll
    for (int mi = 0; mi < 2; ++mi) {
#pragma unroll
      for (int dt = 0; dt < 8; ++dt)
#pragma unroll
        for (int r = 0; r < 4; ++r) o_acc[mi][dt][r] = 0.f;
#pragma unroll
      for (int r = 0; r < 4; ++r) { m_st[mi][r] = -1e30f; l_st[mi][r] = 0.f; }
    }

    stageK(0, smK[0]);
    stageV(0, smV[0]);

    for (int tile = 0; tile < ntiles; ++tile) {
      const int cur = tile & 1;
      if (tile + 1 < ntiles) {
        const int kv1 = (tile + 1) * 64;
        stageK(kv1, smK[cur ^ 1]);
        stageV(kv1, smV[cur ^ 1]);
        asm volatile("s_waitcnt vmcnt(8)" ::: "memory");   // keep prefetch in flight
      } else {
        asm volatile("s_waitcnt vmcnt(0)" ::: "memory");
      }
      __builtin_amdgcn_s_barrier();

      const int kv0 = tile * 64;
      if (kv0 <= wrow_hi) {
        // ---- QK^T ----
        f32x4 sc[2][4];
#pragma unroll
        for (int mi = 0; mi < 2; mi++)
#pragma unroll
          for (int ni = 0; ni < 4; ni++)
#pragma unroll
            for (int r = 0; r < 4; r++) sc[mi][ni][r] = 0.f;
        const bf16* kb = smK[cur];
        __builtin_amdgcn_s_setprio(1);
#pragma unroll
        for (int ks = 0; ks < 4; ++ks) {
          bf16x8 kf[4];
#pragma unroll
          for (int ni = 0; ni < 4; ++ni)
            kf[ni] = *(const bf16x8*)(kb + (ks * 64 + ni * 16 + l15) * 32 + sw * 8);
#pragma unroll
          for (int mi = 0; mi < 2; ++mi)
#pragma unroll
            for (int ni = 0; ni < 4; ++ni)
              sc[mi][ni] = __builtin_amdgcn_mfma_f32_16x16x32_bf16(qf[mi][ks], kf[ni], sc[mi][ni], 0, 0, 0);
        }
        __builtin_amdgcn_s_setprio(0);

        // ---- online softmax (exp2 domain, defer-max, per-lane l) ----
#pragma unroll
        for (int mi = 0; mi < 2; ++mi) {
          const int mrow0 = wrow0 + mi * 16;
          const bool needmask = (kv0 + 63 > mrow0);   // wave-uniform
#pragma unroll
          for (int r = 0; r < 4; ++r) {
            const int qg = mrow0 + quad * 4 + r;
            float xs[4];
            float vmax = -1e30f;
            if (needmask) {
#pragma unroll
              for (int ni = 0; ni < 4; ++ni) {
                const int kg = kv0 + ni * 16 + l15;
                float xv = sc[mi][ni][r] * C;
                xv = (kg > qg) ? -1e30f : xv;
                xs[ni] = xv;
                vmax = fmaxf(vmax, xv);
              }
            } else {
#pragma unroll
              for (int ni = 0; ni < 4; ++ni) {
                const float xv = sc[mi][ni][r] * C;
                xs[ni] = xv;
                vmax = fmaxf(vmax, xv);
              }
            }
            float m_old = m_st[mi][r];
            if (!__all(vmax <= m_old + 8.f)) {        // rare after tile 0
#pragma unroll
              for (int off = 1; off < 16; off <<= 1)
                vmax = fmaxf(vmax, __shfl_xor(vmax, off, 64));
              const float mnew  = fmaxf(m_old, vmax);
              const float alpha = __builtin_amdgcn_exp2f(m_old - mnew);
              l_st[mi][r] *= alpha;
#pragma unroll
              for (int dt = 0; dt < 8; ++dt) o_acc[mi][dt][r] *= alpha;
              m_st[mi][r] = mnew;
              m_old = mnew;
            }
            float ps = 0.f;
#pragma unroll
            for (int ni = 0; ni < 4; ++ni) {
              const float p = __builtin_amdgcn_exp2f(xs[ni] - m_old);
              ps += p;
              myP[(mi * 16 + quad * 4 + r) * 72 + ni * 16 + l15] = __float2bfloat16(p);
            }
            l_st[mi][r] += ps;   // per-lane partial; reduced once in epilogue
          }
        }

        // ---- P @ V (per-wave P, no barrier needed) ----
        const bf16* vb = smV[cur];
        __builtin_amdgcn_s_setprio(1);
#pragma unroll
        for (int ks2 = 0; ks2 < 2; ++ks2) {
          bf16x8 pa[2];
#pragma unroll
          for (int mi = 0; mi < 2; ++mi)
            pa[mi] = *(const bf16x8*)(myP + (mi * 16 + l15) * 72 + ks2 * 32 + quad * 8);
#pragma unroll
          for (int dt = 0; dt < 8; ++dt) {
            const bf16x8 vf = *(const bf16x8*)(vb + (ks2 * 128 + dt * 16 + l15) * 32 + sw * 8);
#pragma unroll
            for (int mi = 0; mi < 2; ++mi)
              o_acc[mi][dt] = __builtin_amdgcn_mfma_f32_16x16x32_bf16(pa[mi], vf, o_acc[mi][dt], 0, 0, 0);
          }
        }
        __builtin_amdgcn_s_setprio(0);
      }
      __builtin_amdgcn_s_barrier();   // all reads of buf[cur] done before reuse
    }

    // ---- epilogue: reduce l across the 16-lane row groups, write O/l ----
#pragma unroll
    for (int mi = 0; mi < 2; ++mi) {
#pragma unroll
      for (int r = 0; r < 4; ++r) {
        float l = l_st[mi][r];
#pragma unroll
        for (int off = 1; off < 16; off <<= 1) l += __shfl_xor(l, off, 64);
        const float rl = 1.f / l;
        const int sg = qbase + w * 32 + mi * 16 + quad * 4 + r;
        const size_t rowoff = hb + (size_t)sg * HD;
#pragma unroll
        for (int dt = 0; dt < 8; ++dt)
          attn_out[rowoff + dt * 16 + l15] = __float2bfloat16(o_acc[mi][dt][r] * rl);
      }
    }
  }
}

// ---------------------------------------------------------------------------
// Kernel 3: out = attn @ w_out^T + b_out, attn stored [b,h,s,d]
// (logical A[m=b*2048+s][k=h*128+d]). OUTPUT FLOAT32. BK=64 + swizzle.
// ---------------------------------------------------------------------------
__global__ __launch_bounds__(256) void gemm_out_k(
    const bf16* __restrict__ attn, const bf16* __restrict__ w,
    const float* __restrict__ bias, float* __restrict__ out)
{
  __shared__ alignas(16) bf16 sA[128 * 64];
  __shared__ alignas(16) bf16 sW[128 * 64];
  const int n0 = blockIdx.x * 128;
  const int m0 = blockIdx.y * 128;

  const int t    = threadIdx.x;
  const int lane = t & 63, quad = lane >> 4, l15 = lane & 15;
  const int wave = t >> 6;
  const int wm0  = (wave >> 1) * 64, wn0 = (wave & 1) * 64;

  f32x4 acc[4][4];
#pragma unroll
  for (int mi = 0; mi < 4; mi++)
#pragma unroll
    for (int ni = 0; ni < 4; ni++)
#pragma unroll
      for (int r = 0; r < 4; r++) acc[mi][ni][r] = 0.f;

  for (int k0 = 0; k0 < EMB; k0 += 64) {
    const int h  = k0 >> 7;          // 64-wide K range never crosses a head
    const int d0 = k0 & 127;
#pragma unroll
    for (int i = 0; i < 4; i++) {
      const int lin = i * 256 + t;              // 0..1023
      const int row = lin >> 3;                 // 0..127
      const int c16 = lin & 7;
      const int col = (c16 ^ (row & 7)) * 8;    // inverse-swizzled source col
      const int m   = m0 + row;
      const int b   = m >> 11;
      const int s   = m & 2047;
      glds16(attn + ((size_t)(b * NH + h) * S_LEN + s) * HD + d0 + col,
             sA + (size_t)lin * 8);
      glds16(w + (size_t)(n0 + row) * EMB + k0 + col, sW + (size_t)lin * 8);
    }
    __syncthreads();
    bf16x8 af[4][2], wf[4][2];
#pragma unroll
    for (int mi = 0; mi < 4; mi++) {
      const int r = wm0 + mi * 16 + l15;
#pragma unroll
      for (int kk = 0; kk < 2; kk++) {
        const int ch = (kk * 4 + quad) ^ (r & 7);
        af[mi][kk] = *(const bf16x8*)(sA + r * 64 + ch * 8);
      }
    }
#pragma unroll
    for (int ni = 0; ni < 4; ni++) {
      const int r = wn0 + ni * 16 + l15;
#pragma unroll
      for (int kk = 0; kk < 2; kk++) {
        const int ch = (kk * 4 + quad) ^ (r & 7);
        wf[ni][kk] = *(const bf16x8*)(sW + r * 64 + ch * 8);
      }
    }
#pragma unroll
    for (int mi = 0; mi < 4; mi++)
#pragma unroll
      for (int ni = 0; ni < 4; ni++)
#pragma unroll
        for (int kk = 0; kk < 2; kk++)
          acc[mi][ni] = __builtin_amdgcn_mfma_f32_16x16x32_bf16(af[mi][kk], wf[ni][kk], acc[mi][ni], 0, 0, 0);
    __syncthreads();
  }

#pragma unroll
  for (int mi = 0; mi < 4; mi++) {
#pragma unroll
    for (int ni = 0; ni < 4; ni++) {
      const int n_g = n0 + wn0 + ni * 16 + l15;
      const float bv = bias[n_g];
#pragma unroll
      for (int r = 0; r < 4; r++) {
        const int m_g = m0 + wm0 + mi * 16 + quad * 4 + r;
        out[(size_t)m_g * EMB + n_g] = acc[mi][ni][r] + bv;   // f32 store
      }
    }
  }
}

// ---------------------------------------------------------------------------
// Workspace layout (96 MiB):
//   [ 0,16)  MiB: xb  bf16 (x converted) -> attn output [b,h,s,d] after QKV
//   [16,40)  MiB: wqb bf16 (w_qkv converted)
//   [40,48)  MiB: wob bf16 (w_out converted)
//   [48,64)  MiB: q [b,h,s,d]
//   [64,80)  MiB: k [b,h,s,d]
//   [80,96)  MiB: v_t [b,h,d,s] (written directly transposed by gemm_qkv_k)
// ---------------------------------------------------------------------------
extern "C" void kernel_launch(void* const* d_in, const int* in_sizes, int n_in,
                              void* d_out, int out_size, void* d_ws, size_t ws_size,
                              hipStream_t stream)
{
  const float* x_f     = (const float*)d_in[0];
  // d_in[1] = attn_mask (causal triu) — known analytically, ignored.
  const float* w_qkv_f = (const float*)d_in[2];
  const float* b_qkv   = (const float*)d_in[3];
  const float* w_out_f = (const float*)d_in[4];
  const float* b_out   = (const float*)d_in[5];
  float* out = (float*)d_out;   // reference output dtype is float32

  char* ws = (char*)d_ws;
  const size_t MB = 1024 * 1024;
  bf16* xb   = (bf16*)(ws);
  bf16* wqb  = (bf16*)(ws + 16 * MB);
  bf16* wob  = (bf16*)(ws + 40 * MB);
  bf16* q_ws = (bf16*)(ws + 48 * MB);
  bf16* k_ws = (bf16*)(ws + 64 * MB);
  bf16* v_t  = (bf16*)(ws + 80 * MB);
  bf16* attn = xb;   // xb dead after gemm_qkv_k; distinct from q_ws (no alias)

  cvt3_k<<<dim3(24576), 256, 0, stream>>>(x_f, xb, w_qkv_f, wqb, w_out_f, wob);

  gemm_qkv_k<<<dim3(48, 32), 256, 0, stream>>>(xb, wqb, b_qkv, q_ws, k_ws, v_t);
  attn_k<<<dim3(256), 256, 0, stream>>>(q_ws, k_ws, v_t, attn);
  gemm_out_k<<<dim3(16, 32), 256, 0, stream>>>(attn, wob, b_out, out);
}

// Round 8
// 403.929 us; speedup vs baseline: 1.1487x; 1.0790x over previous
//
#include <hip/hip_runtime.h>
#include <hip/hip_bf16.h>
#include <stdint.h>

typedef __hip_bfloat16 bf16;
typedef __bf16 bf16x8 __attribute__((ext_vector_type(8)));
typedef float f32x4 __attribute__((ext_vector_type(4)));

#define S_LEN 2048
#define EMB   2048
#define NH    16
#define HD    128

// async global->LDS, 16B per lane. LDS dest must be wave-uniform base + lane*16.
__device__ __forceinline__ void glds16(const void* g, void* l) {
  __builtin_amdgcn_global_load_lds(
      (__attribute__((address_space(1))) void*)g,
      (__attribute__((address_space(3))) void*)l,
      16, 0, 0);
}

// ---------------------------------------------------------------------------
// Kernel 0: fused f32 -> bf16 conversion of x, w_qkv, w_out (one launch).
// ---------------------------------------------------------------------------
__global__ __launch_bounds__(256) void cvt3_k(
    const float* __restrict__ xa, bf16* __restrict__ xo,
    const float* __restrict__ wa, bf16* __restrict__ wo1,
    const float* __restrict__ oa, bf16* __restrict__ oo)
{
  const int bid = blockIdx.x;
  const float* src; bf16* dst; int i;
  if (bid < 8192)       { src = xa; dst = xo;  i = bid * 256 + threadIdx.x; }
  else if (bid < 20480) { src = wa; dst = wo1; i = (bid - 8192) * 256 + threadIdx.x; }
  else                  { src = oa; dst = oo;  i = (bid - 20480) * 256 + threadIdx.x; }
  const float4 v = ((const float4*)src)[i];
  bf16 tmp[4];
  tmp[0] = __float2bfloat16(v.x);
  tmp[1] = __float2bfloat16(v.y);
  tmp[2] = __float2bfloat16(v.z);
  tmp[3] = __float2bfloat16(v.w);
  ((uint2*)dst)[i] = *(const uint2*)tmp;
}

// ===========================================================================
// GEMM geometry (both GEMMs): 128x128 tile, BK=64, 256 thr/4 waves,
// per-wave 64x64. LDS 32KB. R7-measured: qkv 139.7us, conflicts 0.
// T2 XOR swizzle: 16B-chunk ^= (row&7); inverse-swizzled global source +
// linear glds dest + swizzled ds_read (both-sides involution).
// ===========================================================================

// ---------------------------------------------------------------------------
// Kernel 1: qkv = x @ w_qkv^T + b_qkv  (R7-measured version — FROZEN).
// ---------------------------------------------------------------------------
__global__ __launch_bounds__(256) void gemm_qkv_k(
    const bf16* __restrict__ x, const bf16* __restrict__ w,
    const float* __restrict__ bias,
    bf16* __restrict__ q_ws, bf16* __restrict__ k_ws, bf16* __restrict__ v_t)
{
  __shared__ alignas(16) bf16 sA[128 * 64];
  __shared__ alignas(16) bf16 sW[128 * 64];
  const int n0 = blockIdx.x * 128;
  const int m0 = blockIdx.y * 128;

  const int t    = threadIdx.x;
  const int lane = t & 63, quad = lane >> 4, l15 = lane & 15;
  const int wave = t >> 6;
  const int wm0  = (wave >> 1) * 64, wn0 = (wave & 1) * 64;

  f32x4 acc[4][4];
#pragma unroll
  for (int mi = 0; mi < 4; mi++)
#pragma unroll
    for (int ni = 0; ni < 4; ni++)
#pragma unroll
      for (int r = 0; r < 4; r++) acc[mi][ni][r] = 0.f;

  for (int k0 = 0; k0 < EMB; k0 += 64) {
#pragma unroll
    for (int i = 0; i < 4; i++) {
      const int lin = i * 256 + t;              // 0..1023
      const int row = lin >> 3;                 // 0..127
      const int c16 = lin & 7;                  // 16B chunk in row
      const int col = (c16 ^ (row & 7)) * 8;    // inverse-swizzled source col
      glds16(x + (size_t)(m0 + row) * EMB + k0 + col, sA + (size_t)lin * 8);
      glds16(w + (size_t)(n0 + row) * EMB + k0 + col, sW + (size_t)lin * 8);
    }
    __syncthreads();
    bf16x8 af[4][2], wf[4][2];
#pragma unroll
    for (int mi = 0; mi < 4; mi++) {
      const int r = wm0 + mi * 16 + l15;
#pragma unroll
      for (int kk = 0; kk < 2; kk++) {
        const int ch = (kk * 4 + quad) ^ (r & 7);
        af[mi][kk] = *(const bf16x8*)(sA + r * 64 + ch * 8);
      }
    }
#pragma unroll
    for (int ni = 0; ni < 4; ni++) {
      const int r = wn0 + ni * 16 + l15;
#pragma unroll
      for (int kk = 0; kk < 2; kk++) {
        const int ch = (kk * 4 + quad) ^ (r & 7);
        wf[ni][kk] = *(const bf16x8*)(sW + r * 64 + ch * 8);
      }
    }
#pragma unroll
    for (int mi = 0; mi < 4; mi++)
#pragma unroll
      for (int ni = 0; ni < 4; ni++)
#pragma unroll
        for (int kk = 0; kk < 2; kk++)
          acc[mi][ni] = __builtin_amdgcn_mfma_f32_16x16x32_bf16(af[mi][kk], wf[ni][kk], acc[mi][ni], 0, 0, 0);
    __syncthreads();
  }

  const int which = n0 >> 11;                 // 0=q,1=k,2=v (whole block same)
  bf16* dst = (which == 0) ? q_ws : ((which == 1) ? k_ws : v_t);

#pragma unroll
  for (int mi = 0; mi < 4; mi++) {
#pragma unroll
    for (int ni = 0; ni < 4; ni++) {
      const int n_g = n0 + wn0 + ni * 16 + l15;
      const int h   = (n_g >> 7) & 15;
      const int d   = n_g & 127;
      const float bv = bias[n_g];
#pragma unroll
      for (int r = 0; r < 4; r++) {
        const int m_g = m0 + wm0 + mi * 16 + quad * 4 + r;
        const int b   = m_g >> 11;
        const int s   = m_g & 2047;
        const size_t idx = (which == 2)
            ? ((size_t)(b * NH + h) * HD + d) * S_LEN + s      // V: [b,h,d,s]
            : ((size_t)(b * NH + h) * S_LEN + s) * HD + d;     // Q/K: [b,h,s,d]
        dst[idx] = __float2bfloat16(acc[mi][ni][r] + bv);
      }
    }
  }
}

// ---------------------------------------------------------------------------
// Kernel 2: causal flash attention. R5 outer structure (heavy+light Q-tile
// pair per block, grid 256; K/V dbuf + counted vmcnt; XOR-swizzled LDS;
// exp2 softmax diet) but EIGHT waves (512 thr), each wave owns 16 Q-rows
// -> 2 waves/SIMD within one block: co-wave hides vmcnt/lgkm/barrier
// stalls (m114 pipe overlap). setprio REMOVED (8 lockstep waves = m190
// regime; suspected R6 regression cause). LDS 82KB -> exactly 1 block/CU.
// ---------------------------------------------------------------------------
__global__ __launch_bounds__(512, 2) void attn_k(
    const bf16* __restrict__ q_ws, const bf16* __restrict__ k_ws,
    const bf16* __restrict__ v_t, bf16* __restrict__ attn_out)
{
  __shared__ alignas(16) bf16 smK[2][8192];
  __shared__ alignas(16) bf16 smV[2][8192];
  __shared__ alignas(16) bf16 smP[8][16 * 72];

  const int t    = threadIdx.x;
  const int lane = t & 63, quad = lane >> 4, l15 = lane & 15;
  const int w    = t >> 6;                  // 0..7
  const int bh   = blockIdx.x >> 3;
  const int pr   = blockIdx.x & 7;
  const size_t hb = (size_t)bh * (S_LEN * HD);
  bf16* myP = smP[w];
  const float C = 0.12751745f;   // (1/sqrt(128)) * log2(e)
  const int sw = quad ^ ((l15 >> 1) & 3);   // swizzled 16B-slot for K/V reads

  // 512 threads: 2 glds/thread per K tile, 2 per V tile (lin decode unchanged)
  auto stageK = [&](int kv0, bf16* dst) {
#pragma unroll
    for (int i = 0; i < 2; i++) {
      const int lin = i * 512 + t;           // 0..1023
      const int cc  = lin >> 8;              // k-chunk 0..3
      const int row = (lin >> 2) & 63;
      const int sl  = (lin & 3) ^ ((row >> 1) & 3);   // inverse-swizzled source
      glds16(k_ws + hb + (size_t)(kv0 + row) * HD + cc * 32 + sl * 8,
             dst + (size_t)lin * 8);
    }
  };
  auto stageV = [&](int kv0, bf16* dst) {
#pragma unroll
    for (int i = 0; i < 2; i++) {
      const int lin = i * 512 + t;
      const int cc  = lin >> 9;              // s-chunk 0..1
      const int row = (lin >> 2) & 127;      // d index
      const int sl  = (lin & 3) ^ ((row >> 1) & 3);
      glds16(v_t + hb + (size_t)row * S_LEN + kv0 + cc * 32 + sl * 8,
             dst + (size_t)lin * 8);
    }
  };

  for (int ph = 0; ph < 2; ++ph) {
    const int qt     = ph ? pr : (15 - pr);   // heavy tile first
    const int qbase  = qt * 128;
    const int ntiles = 2 * qt + 2;
    const int wrow0  = qbase + w * 16;        // this wave's 16 Q rows
    const int wrow_hi = wrow0 + 15;

    // Q fragments straight from global (registers; no LDS staging)
    bf16x8 qf[4];
#pragma unroll
    for (int ks = 0; ks < 4; ++ks)
      qf[ks] = *(const bf16x8*)(q_ws + hb + (size_t)(wrow0 + l15) * HD + ks * 32 + quad * 8);

    f32x4 o_acc[8];
    float m_st[4], l_st[4];
#pragma unroll
    for (int dt = 0; dt < 8; ++dt)
#pragma unroll
      for (int r = 0; r < 4; ++r) o_acc[dt][r] = 0.f;
#pragma unroll
    for (int r = 0; r < 4; ++r) { m_st[r] = -1e30f; l_st[r] = 0.f; }

    stageK(0, smK[0]);
    stageV(0, smV[0]);

    for (int tile = 0; tile < ntiles; ++tile) {
      const int cur = tile & 1;
      if (tile + 1 < ntiles) {
        const int kv1 = (tile + 1) * 64;
        stageK(kv1, smK[cur ^ 1]);
        stageV(kv1, smV[cur ^ 1]);
        asm volatile("s_waitcnt vmcnt(4)" ::: "memory");   // keep prefetch in flight
      } else {
        asm volatile("s_waitcnt vmcnt(0)" ::: "memory");
      }
      __builtin_amdgcn_s_barrier();

      const int kv0 = tile * 64;
      if (kv0 <= wrow_hi) {
        // ---- QK^T (16 q-rows x 64 kv) ----
        f32x4 sc[4];
#pragma unroll
        for (int ni = 0; ni < 4; ni++)
#pragma unroll
          for (int r = 0; r < 4; r++) sc[ni][r] = 0.f;
        const bf16* kb = smK[cur];
#pragma unroll
        for (int ks = 0; ks < 4; ++ks) {
          bf16x8 kf[4];
#pragma unroll
          for (int ni = 0; ni < 4; ++ni)
            kf[ni] = *(const bf16x8*)(kb + (ks * 64 + ni * 16 + l15) * 32 + sw * 8);
#pragma unroll
          for (int ni = 0; ni < 4; ++ni)
            sc[ni] = __builtin_amdgcn_mfma_f32_16x16x32_bf16(qf[ks], kf[ni], sc[ni], 0, 0, 0);
        }

        // ---- online softmax (exp2 domain, defer-max, per-lane l) ----
        const bool needmask = (kv0 + 63 > wrow0);   // wave-uniform
#pragma unroll
        for (int r = 0; r < 4; ++r) {
          const int qg = wrow0 + quad * 4 + r;
          float xs[4];
          float vmax = -1e30f;
          if (needmask) {
#pragma unroll
            for (int ni = 0; ni < 4; ++ni) {
              const int kg = kv0 + ni * 16 + l15;
              float xv = sc[ni][r] * C;
              xv = (kg > qg) ? -1e30f : xv;
              xs[ni] = xv;
              vmax = fmaxf(vmax, xv);
            }
          } else {
#pragma unroll
            for (int ni = 0; ni < 4; ++ni) {
              const float xv = sc[ni][r] * C;
              xs[ni] = xv;
              vmax = fmaxf(vmax, xv);
            }
          }
          float m_old = m_st[r];
          if (!__all(vmax <= m_old + 8.f)) {        // rare after tile 0
#pragma unroll
            for (int off = 1; off < 16; off <<= 1)
              vmax = fmaxf(vmax, __shfl_xor(vmax, off, 64));
            const float mnew  = fmaxf(m_old, vmax);
            const float alpha = __builtin_amdgcn_exp2f(m_old - mnew);
            l_st[r] *= alpha;
#pragma unroll
            for (int dt = 0; dt < 8; ++dt) o_acc[dt][r] *= alpha;
            m_st[r] = mnew;
            m_old = mnew;
          }
          float ps = 0.f;
#pragma unroll
          for (int ni = 0; ni < 4; ++ni) {
            const float p = __builtin_amdgcn_exp2f(xs[ni] - m_old);
            ps += p;
            myP[(quad * 4 + r) * 72 + ni * 16 + l15] = __float2bfloat16(p);
          }
          l_st[r] += ps;   // per-lane partial; reduced once in epilogue
        }

        // ---- P @ V (per-wave P, no barrier needed) ----
        const bf16* vb = smV[cur];
#pragma unroll
        for (int ks2 = 0; ks2 < 2; ++ks2) {
          const bf16x8 pa = *(const bf16x8*)(myP + l15 * 72 + ks2 * 32 + quad * 8);
#pragma unroll
          for (int dt = 0; dt < 8; ++dt) {
            const bf16x8 vf = *(const bf16x8*)(vb + (ks2 * 128 + dt * 16 + l15) * 32 + sw * 8);
            o_acc[dt] = __builtin_amdgcn_mfma_f32_16x16x32_bf16(pa, vf, o_acc[dt], 0, 0, 0);
          }
        }
      }
      __builtin_amdgcn_s_barrier();   // all reads of buf[cur] done before reuse
    }

    // ---- epilogue: reduce l across the 16-lane row groups, write O/l ----
#pragma unroll
    for (int r = 0; r < 4; ++r) {
      float l = l_st[r];
#pragma unroll
      for (int off = 1; off < 16; off <<= 1) l += __shfl_xor(l, off, 64);
      const float rl = 1.f / l;
      const int sg = wrow0 + quad * 4 + r;
      const size_t rowoff = hb + (size_t)sg * HD;
#pragma unroll
      for (int dt = 0; dt < 8; ++dt)
        attn_out[rowoff + dt * 16 + l15] = __float2bfloat16(o_acc[dt][r] * rl);
    }
  }
}

// ---------------------------------------------------------------------------
// Kernel 3: out = attn @ w_out^T + b_out  (R7-measured version — FROZEN).
// attn stored [b,h,s,d] (logical A[m=b*2048+s][k=h*128+d]). OUTPUT FLOAT32.
// ---------------------------------------------------------------------------
__global__ __launch_bounds__(256) void gemm_out_k(
    const bf16* __restrict__ attn, const bf16* __restrict__ w,
    const float* __restrict__ bias, float* __restrict__ out)
{
  __shared__ alignas(16) bf16 sA[128 * 64];
  __shared__ alignas(16) bf16 sW[128 * 64];
  const int n0 = blockIdx.x * 128;
  const int m0 = blockIdx.y * 128;

  const int t    = threadIdx.x;
  const int lane = t & 63, quad = lane >> 4, l15 = lane & 15;
  const int wave = t >> 6;
  const int wm0  = (wave >> 1) * 64, wn0 = (wave & 1) * 64;

  f32x4 acc[4][4];
#pragma unroll
  for (int mi = 0; mi < 4; mi++)
#pragma unroll
    for (int ni = 0; ni < 4; ni++)
#pragma unroll
      for (int r = 0; r < 4; r++) acc[mi][ni][r] = 0.f;

  for (int k0 = 0; k0 < EMB; k0 += 64) {
    const int h  = k0 >> 7;          // 64-wide K range never crosses a head
    const int d0 = k0 & 127;
#pragma unroll
    for (int i = 0; i < 4; i++) {
      const int lin = i * 256 + t;              // 0..1023
      const int row = lin >> 3;                 // 0..127
      const int c16 = lin & 7;
      const int col = (c16 ^ (row & 7)) * 8;    // inverse-swizzled source col
      const int m   = m0 + row;
      const int b   = m >> 11;
      const int s   = m & 2047;
      glds16(attn + ((size_t)(b * NH + h) * S_LEN + s) * HD + d0 + col,
             sA + (size_t)lin * 8);
      glds16(w + (size_t)(n0 + row) * EMB + k0 + col, sW + (size_t)lin * 8);
    }
    __syncthreads();
    bf16x8 af[4][2], wf[4][2];
#pragma unroll
    for (int mi = 0; mi < 4; mi++) {
      const int r = wm0 + mi * 16 + l15;
#pragma unroll
      for (int kk = 0; kk < 2; kk++) {
        const int ch = (kk * 4 + quad) ^ (r & 7);
        af[mi][kk] = *(const bf16x8*)(sA + r * 64 + ch * 8);
      }
    }
#pragma unroll
    for (int ni = 0; ni < 4; ni++) {
      const int r = wn0 + ni * 16 + l15;
#pragma unroll
      for (int kk = 0; kk < 2; kk++) {
        const int ch = (kk * 4 + quad) ^ (r & 7);
        wf[ni][kk] = *(const bf16x8*)(sW + r * 64 + ch * 8);
      }
    }
#pragma unroll
    for (int mi = 0; mi < 4; mi++)
#pragma unroll
      for (int ni = 0; ni < 4; ni++)
#pragma unroll
        for (int kk = 0; kk < 2; kk++)
          acc[mi][ni] = __builtin_amdgcn_mfma_f32_16x16x32_bf16(af[mi][kk], wf[ni][kk], acc[mi][ni], 0, 0, 0);
    __syncthreads();
  }

#pragma unroll
  for (int mi = 0; mi < 4; mi++) {
#pragma unroll
    for (int ni = 0; ni < 4; ni++) {
      const int n_g = n0 + wn0 + ni * 16 + l15;
      const float bv = bias[n_g];
#pragma unroll
      for (int r = 0; r < 4; r++) {
        const int m_g = m0 + wm0 + mi * 16 + quad * 4 + r;
        out[(size_t)m_g * EMB + n_g] = acc[mi][ni][r] + bv;   // f32 store
      }
    }
  }
}

// ---------------------------------------------------------------------------
// Workspace layout (96 MiB):
//   [ 0,16)  MiB: xb  bf16 (x converted) -> attn output [b,h,s,d] after QKV
//   [16,40)  MiB: wqb bf16 (w_qkv converted)
//   [40,48)  MiB: wob bf16 (w_out converted)
//   [48,64)  MiB: q [b,h,s,d]
//   [64,80)  MiB: k [b,h,s,d]
//   [80,96)  MiB: v_t [b,h,d,s] (written directly transposed by gemm_qkv_k)
// ---------------------------------------------------------------------------
extern "C" void kernel_launch(void* const* d_in, const int* in_sizes, int n_in,
                              void* d_out, int out_size, void* d_ws, size_t ws_size,
                              hipStream_t stream)
{
  const float* x_f     = (const float*)d_in[0];
  // d_in[1] = attn_mask (causal triu) — known analytically, ignored.
  const float* w_qkv_f = (const float*)d_in[2];
  const float* b_qkv   = (const float*)d_in[3];
  const float* w_out_f = (const float*)d_in[4];
  const float* b_out   = (const float*)d_in[5];
  float* out = (float*)d_out;   // reference output dtype is float32

  char* ws = (char*)d_ws;
  const size_t MB = 1024 * 1024;
  bf16* xb   = (bf16*)(ws);
  bf16* wqb  = (bf16*)(ws + 16 * MB);
  bf16* wob  = (bf16*)(ws + 40 * MB);
  bf16* q_ws = (bf16*)(ws + 48 * MB);
  bf16* k_ws = (bf16*)(ws + 64 * MB);
  bf16* v_t  = (bf16*)(ws + 80 * MB);
  bf16* attn = xb;   // xb dead after gemm_qkv_k; distinct from q_ws (no alias)

  cvt3_k<<<dim3(24576), 256, 0, stream>>>(x_f, xb, w_qkv_f, wqb, w_out_f, wob);

  gemm_qkv_k<<<dim3(48, 32), 256, 0, stream>>>(xb, wqb, b_qkv, q_ws, k_ws, v_t);
  attn_k<<<dim3(256), 512, 0, stream>>>(q_ws, k_ws, v_t, attn);
  gemm_out_k<<<dim3(16, 32), 256, 0, stream>>>(attn, wob, b_out, out);
}